// Round 2
// baseline (125.234 us; speedup 1.0000x reference)
//
#include <hip/hip_runtime.h>

#define BLK 256
#define WPT 10                  // float4 per lane -> 2560-element capacity per WAVE
#define WCAP (WPT * 64 * 4)     // 2560 (group mean 2048, max ~2250 for this input)
#define CCAP 320                // candidate buffer per wave: c<=64 exact; <=CCAP wave-Michelot; else register Michelot
#define SWIN 8192               // boundary search half-window: +-5.7 sigma of Binomial(N, g/B) jitter

// ---------- wave-local reductions (64-lane) ----------

__device__ __forceinline__ float wave_max(float v) {
#pragma unroll
  for (int o = 32; o; o >>= 1) v = fmaxf(v, __shfl_xor(v, o));
  return v;
}
__device__ __forceinline__ float wave_sum(float v) {
#pragma unroll
  for (int o = 32; o; o >>= 1) v += __shfl_xor(v, o);
  return v;
}
__device__ __forceinline__ int wave_sum_i(int v) {
#pragma unroll
  for (int o = 32; o; o >>= 1) v += __shfl_xor(v, o);
  return v;
}

// ---------- windowed lower_bound on the sorted batch array ----------
// first i in [0,N] with batch[i] >= b. est is the statistical guess g*N/B;
// the +-SWIN window covers ~5.7 sigma of the boundary jitter. If the window
// check fails (P ~ 1e-8 per boundary), widen that side to the full range.
// ~14 dependent scalar probes in the common case, top probes L2/L3-hot
// (shared across all waves). This replaces the R5 build_starts kernel's
// full 33.5 MB coalesced stream of batch (and its separate launch).

__device__ __forceinline__ int lower_bound_win(const int* __restrict__ batch,
                                               int N, int b, int est) {
  int lo = est - SWIN; if (lo < 0) lo = 0;
  int hi = est + SWIN; if (hi > N) hi = N;
  if (lo > 0 && batch[lo - 1] >= b) lo = 0;   // window miss: widen left
  if (hi < N && batch[hi] < b) hi = N;        // window miss: widen right
  while (lo < hi) {
    const int mid = (lo + hi) >> 1;
    if (batch[mid] < b) lo = mid + 1; else hi = mid;
  }
  return lo;
}

// ---------- fused kernel: one WAVE per group, finds its own boundaries ----------
// R1 showed kernel-2 restructure is ~neutral: the measured time is dominated by
// harness-fixed dispatches (256 MiB workspace poison fills at ~42 us each), and
// our kernels contribute ~20 us combined. This round deletes the remaining
// controllable overhead: build_starts' 33.5 MB batch stream + its launch +
// the starts[] round-trip, replaced by an in-kernel windowed binary search
// (half-wave dual search: lanes <32 find start, lanes >=32 find end).

extern "C" __global__ void __launch_bounds__(BLK)
sparsemax_fused(const float* __restrict__ x, const int* __restrict__ batch,
                const int* __restrict__ pB, float* __restrict__ out, int N) {
  __shared__ float cand[4][CCAP];     // per-wave candidate buffers
  __shared__ float sorted_[4][64];    // per-wave rank-scatter scratch
  const int tid  = threadIdx.x;
  const int lane = tid & 63;
  const int w    = tid >> 6;
  const int B = *pB;

  for (int g = blockIdx.x * 4 + w; g < B; g += gridDim.x * 4) {
    // ---- phase 0: boundaries via half-wave dual binary search ----
    const int b   = g + (lane >= 32 ? 1 : 0);
    const int est = (int)(((long long)b * N) / B);
    const int sb  = lower_bound_win(batch, N, b, est);
    const int s   = __shfl(sb, 0);
    const int e   = __shfl(sb, 32);
    const int n = e - s;
    if (n <= 0) continue;
    const int a0 = s & ~3;               // 16B-aligned load base

    if (e - a0 <= WCAP) {
      // ---- phase 1: aligned float4 global -> registers, fused max ----
      float4 r[WPT];
      float lmax = -INFINITY;
#pragma unroll
      for (int j = 0; j < WPT; ++j) {
        const int idx = a0 + (j * 64 + lane) * 4;
        float4 v = make_float4(-INFINITY, -INFINITY, -INFINITY, -INFINITY);
        if (idx < e) {
          if (idx + 4 <= N) {
            v = *(const float4*)(x + idx);
          } else {                        // buffer tail (last group only)
            if (idx + 0 < N) v.x = x[idx + 0];
            if (idx + 1 < N) v.y = x[idx + 1];
            if (idx + 2 < N) v.z = x[idx + 2];
            if (idx + 3 < N) v.w = x[idx + 3];
          }
          if (idx + 0 < s || idx + 0 >= e) v.x = -INFINITY;  // mask other groups
          if (idx + 1 < s || idx + 1 >= e) v.y = -INFINITY;
          if (idx + 2 < s || idx + 2 >= e) v.z = -INFINITY;
          if (idx + 3 < s || idx + 3 >= e) v.w = -INFINITY;
        }
        r[j] = v;
        lmax = fmaxf(lmax, fmaxf(fmaxf(v.x, v.y), fmaxf(v.z, v.w)));
      }
      const float gmax = wave_max(lmax);
      const float thr = gmax - 1.0f;     // tau >= -1 bound (outputs sum to 1)

      // ---- phase 2: ballot compaction; cnt is wave-uniform in a register ----
      int cnt = 0;
      float wsum = 0.0f;                 // this lane's candidate sum (shifted)
#pragma unroll
      for (int j = 0; j < WPT; ++j) {
        const float vv[4] = {r[j].x, r[j].y, r[j].z, r[j].w};
#pragma unroll
        for (int t = 0; t < 4; ++t) {
          const bool p = vv[t] > thr;
          const unsigned long long bal = __ballot(p);
          if (bal) {                     // wave-uniform branch (s_cbranch)
            if (p) {
              const int off = cnt + __popcll(bal & ((1ull << lane) - 1ull));
              if (off < CCAP) cand[w][off] = vv[t];
              wsum += vv[t] - gmax;
            }
            cnt += __popcll(bal);        // ballot is uniform -> no atomic needed
          }
        }
      }
      wsum = wave_sum(wsum);
      const int c = cnt;                 // >= 1 (max element always passes)

      float tau;
      if (c <= 64) {
        // exact rank-sort + shfl prefix-scan + ballot solve (every wave)
        const float v = (lane < c) ? cand[w][lane] - gmax : 0.0f;
        int rank = 0;
        for (int q = 0; q < c; ++q) {
          const float t = cand[w][q] - gmax;
          rank += (t > v) || (t == v && q < lane);   // unique ranks
        }
        if (lane < c) sorted_[w][rank] = v;          // sorted_[w][0] == 0
        const float sv = (lane < c) ? sorted_[w][lane] : 0.0f;  // same-wave DS: in-order
        float cs = sv;
#pragma unroll
        for (int o = 1; o < 64; o <<= 1) {           // inclusive prefix scan
          const float t2 = __shfl_up(cs, o);
          if (lane >= o) cs += t2;
        }
        const int flag = (lane < c) && (sv * (float)(lane + 1) > cs - 1.0f);
        const unsigned long long bal2 = __ballot(flag);  // lane 0 always true
        const int k = 63 - __clzll(bal2);                // support size - 1
        const float csk = __shfl(cs, k);
        tau = (csk - 1.0f) / (float)(k + 1);
      } else if (c <= CCAP) {
        // wave Michelot over LDS candidates
        tau = (wsum - 1.0f) / (float)c;
        int cnt2 = c;
        for (int it = 0; it < 64; ++it) {
          float s2 = 0.0f; int c2 = 0;
          for (int q = lane; q < c; q += 64) {
            const float vs = cand[w][q] - gmax;
            if (vs > tau) { s2 += vs; c2++; }
          }
          s2 = wave_sum(s2); c2 = wave_sum_i(c2);
          if (c2 == cnt2 || c2 == 0) break;
          tau = (s2 - 1.0f) / (float)c2; cnt2 = c2;
        }
      } else {
        // pathological path: Michelot on registers, wave-local (-inf never passes)
        tau = (wsum - 1.0f) / (float)c;
        int cnt2 = c;
        for (int it = 0; it < 64; ++it) {
          float s2 = 0.0f; int c2 = 0;
#pragma unroll
          for (int j = 0; j < WPT; ++j) {
            const float vv[4] = {r[j].x, r[j].y, r[j].z, r[j].w};
#pragma unroll
            for (int t = 0; t < 4; ++t) {
              const float vs = vv[t] - gmax;
              if (vs > tau) { s2 += vs; c2++; }
            }
          }
          s2 = wave_sum(s2); c2 = wave_sum_i(c2);
          if (c2 == cnt2 || c2 == 0) break;
          tau = (s2 - 1.0f) / (float)c2; cnt2 = c2;
        }
      }

      const float sub = tau + gmax;      // unshifted threshold

      // ---- phase 3: store (vector interior, scalar boundary quads) ----
#pragma unroll
      for (int j = 0; j < WPT; ++j) {
        const int idx = a0 + (j * 64 + lane) * 4;
        if (idx >= e) continue;
        if (idx >= s && idx + 4 <= e) {
          float4 o4;
          o4.x = fmaxf(r[j].x - sub, 0.0f);
          o4.y = fmaxf(r[j].y - sub, 0.0f);
          o4.z = fmaxf(r[j].z - sub, 0.0f);
          o4.w = fmaxf(r[j].w - sub, 0.0f);
          *(float4*)(out + idx) = o4;
        } else {
          const float vv[4] = {r[j].x, r[j].y, r[j].z, r[j].w};
#pragma unroll
          for (int t = 0; t < 4; ++t) {
            const int p2 = idx + t;
            if (p2 >= s && p2 < e) out[p2] = fmaxf(vv[t] - sub, 0.0f);
          }
        }
      }
    } else {
      // ---- n > capacity fallback: wave-strided global Michelot (no barriers) ----
      float gmax = -INFINITY;
      for (int i = s + lane; i < e; i += 64) gmax = fmaxf(gmax, x[i]);
      gmax = wave_max(gmax);
      float bs = 0.0f; int bc = 0;
      for (int i = s + lane; i < e; i += 64) {
        const float vs = x[i] - gmax;
        if (vs > -1.0f) { bs += vs; bc++; }
      }
      bs = wave_sum(bs); bc = wave_sum_i(bc);
      float tau = (bs - 1.0f) / (float)bc;
      int cntS = bc;
      for (int it = 0; it < 64; ++it) {
        float s2 = 0.0f; int c2 = 0;
        for (int i = s + lane; i < e; i += 64) {
          const float vs = x[i] - gmax;
          if (vs > tau) { s2 += vs; c2++; }
        }
        s2 = wave_sum(s2); c2 = wave_sum_i(c2);
        if (c2 == cntS || c2 == 0) break;
        tau = (s2 - 1.0f) / (float)c2; cntS = c2;
      }
      const float sub = tau + gmax;
      for (int i = s + lane; i < e; i += 64) out[i] = fmaxf(x[i] - sub, 0.0f);
    }
  }
}

extern "C" void kernel_launch(void* const* d_in, const int* in_sizes, int n_in,
                              void* d_out, int out_size, void* d_ws, size_t ws_size,
                              hipStream_t stream) {
  const float* x     = (const float*)d_in[0];
  const int*   batch = (const int*)d_in[1];   // int32 on device (JAX x64 disabled)
  const int*   pB    = (const int*)d_in[2];
  float*       out   = (float*)d_out;
  const int N = in_sizes[0];

  // single fused launch: one wave per group (1024 blocks x 4 waves = 4096 waves),
  // each wave binary-searches its own boundaries; grid-strides if B > 16384.
  // d_ws intentionally unused (no starts[] scratch anymore).
  (void)d_ws; (void)ws_size;
  sparsemax_fused<<<dim3(1024), dim3(BLK), 0, stream>>>(x, batch, pB, out, N);
}

// Round 3
// 118.874 us; speedup vs baseline: 1.0535x; 1.0535x over previous
//
#include <hip/hip_runtime.h>

#define BLK 256
#define WPT 10                  // float4 per lane -> 2560-element capacity per WAVE
#define WCAP (WPT * 64 * 4)     // 2560 (group mean 2048, max ~2250 for this input)
#define CCAP 320                // candidate buffer per wave: c<=64 exact; <=CCAP wave-Michelot; else register Michelot
#define SSTR 64                 // build_starts sample stride (ints)

// ---------- wave-local reductions (64-lane) ----------

__device__ __forceinline__ float wave_max(float v) {
#pragma unroll
  for (int o = 32; o; o >>= 1) v = fmaxf(v, __shfl_xor(v, o));
  return v;
}
__device__ __forceinline__ float wave_sum(float v) {
#pragma unroll
  for (int o = 32; o; o >>= 1) v += __shfl_xor(v, o);
  return v;
}
__device__ __forceinline__ int wave_sum_i(int v) {
#pragma unroll
  for (int o = 32; o; o >>= 1) v += __shfl_xor(v, o);
  return v;
}

// ---------- kernel 1: sampled boundary detect -> starts[0..B] ----------
// batch is SORTED, so sample endpoints equal <=> no boundary inside the
// sampled interval. Stride-64 sampling touches every 4th cacheline (~8.4 MB
// vs the 33.5 MB full stream of the R1 build_starts), and each changed
// interval is refined with ONE parallel 64-lane contiguous gather + ballot
// (NOT R2's 14-deep serial probe chain -- that was the latency disaster).
// Refine handles any number of boundaries per interval (incl. empty groups),
// so correctness does not depend on the group-size distribution.

extern "C" __global__ void __launch_bounds__(256)
build_starts_sampled(const int* __restrict__ batch, int* __restrict__ starts,
                     const int* __restrict__ pB, int N) {
  const int B = *pB;
  const int lane = threadIdx.x & 63;
  const int w    = threadIdx.x >> 6;
  const int wgid = blockIdx.x * 4 + w;            // global wave id
  const int K = (N + SSTR - 1) / SSTR;            // number of sample intervals

  // head/tail edge writes (one thread in the grid; ~2 iterations typical)
  if (wgid == 0 && lane == 0) {
    const int b0 = batch[0];
    for (int g = 0; g <= b0; ++g) starts[g] = 0;  // leading (possibly empty) groups
    const int bl = batch[N - 1];
    for (int g = bl + 1; g <= B; ++g) starts[g] = N;  // trailing groups + starts[B]
  }

  const int kbase = wgid * 64;
  if (kbase >= K) return;
  const int k = kbase + lane;                     // this lane's interval id

  // interval k endpoints: v0 = batch[k*S], v1 = batch[(k+1)*S] (clamped)
  const long long p0 = (long long)k * SSTR;
  const int v0 = batch[(p0 < N) ? p0 : (N - 1)];
  int v1 = __shfl(v0, lane + 1);                  // lane 63: wrapped garbage, fixed below
  if (lane == 63) {
    const long long p1 = (long long)(k + 1) * SSTR;
    v1 = batch[(p1 < N) ? p1 : (N - 1)];
  }
  const bool changed = (k < K) && (v0 != v1);
  unsigned long long m = __ballot(changed);

  // refine each changed interval: pairs (p-1,p) for p in (A, A+S], one int/lane
  while (m) {
    const int i = __ffsll((long long)m) - 1;
    m &= m - 1;
    const int vA = __shfl(v0, i);                 // batch[A]
    const long long A = (long long)(kbase + i) * SSTR;
    const long long idx = A + 1 + lane;           // pair position p
    const bool act = idx < N;
    int c = vA;
    if (act) c = batch[idx];
    int pv = __shfl_up(c, 1);
    if (lane == 0) pv = vA;
    if (act && pv != c) {                         // boundary at p (pv < c, sorted)
      for (int g = pv + 1; g <= c; ++g) starts[g] = (int)idx;  // empty groups too
    }
  }
}

// ---------- kernel 2: one WAVE per group (R1 structure, verified at parity) ----------

extern "C" __global__ void __launch_bounds__(BLK)
sparsemax_groups(const float* __restrict__ x, const int* __restrict__ starts,
                 const int* __restrict__ pB, float* __restrict__ out, int N) {
  __shared__ float cand[4][CCAP];     // per-wave candidate buffers
  __shared__ float sorted_[4][64];    // per-wave rank-scatter scratch
  const int tid  = threadIdx.x;
  const int lane = tid & 63;
  const int w    = tid >> 6;
  const int B = *pB;

  for (int g = blockIdx.x * 4 + w; g < B; g += gridDim.x * 4) {
    const int s = starts[g];
    const int e = starts[g + 1];
    const int n = e - s;
    if (n <= 0) continue;
    const int a0 = s & ~3;               // 16B-aligned load base

    if (e - a0 <= WCAP) {
      // ---- phase 1: aligned float4 global -> registers, fused max ----
      float4 r[WPT];
      float lmax = -INFINITY;
#pragma unroll
      for (int j = 0; j < WPT; ++j) {
        const int idx = a0 + (j * 64 + lane) * 4;
        float4 v = make_float4(-INFINITY, -INFINITY, -INFINITY, -INFINITY);
        if (idx < e) {
          if (idx + 4 <= N) {
            v = *(const float4*)(x + idx);
          } else {                        // buffer tail (last group only)
            if (idx + 0 < N) v.x = x[idx + 0];
            if (idx + 1 < N) v.y = x[idx + 1];
            if (idx + 2 < N) v.z = x[idx + 2];
            if (idx + 3 < N) v.w = x[idx + 3];
          }
          if (idx + 0 < s || idx + 0 >= e) v.x = -INFINITY;  // mask other groups
          if (idx + 1 < s || idx + 1 >= e) v.y = -INFINITY;
          if (idx + 2 < s || idx + 2 >= e) v.z = -INFINITY;
          if (idx + 3 < s || idx + 3 >= e) v.w = -INFINITY;
        }
        r[j] = v;
        lmax = fmaxf(lmax, fmaxf(fmaxf(v.x, v.y), fmaxf(v.z, v.w)));
      }
      const float gmax = wave_max(lmax);
      const float thr = gmax - 1.0f;     // tau >= -1 bound (outputs sum to 1)

      // ---- phase 2: ballot compaction; cnt is wave-uniform in a register ----
      int cnt = 0;
      float wsum = 0.0f;                 // this lane's candidate sum (shifted)
#pragma unroll
      for (int j = 0; j < WPT; ++j) {
        const float vv[4] = {r[j].x, r[j].y, r[j].z, r[j].w};
#pragma unroll
        for (int t = 0; t < 4; ++t) {
          const bool p = vv[t] > thr;
          const unsigned long long bal = __ballot(p);
          if (bal) {                     // wave-uniform branch (s_cbranch)
            if (p) {
              const int off = cnt + __popcll(bal & ((1ull << lane) - 1ull));
              if (off < CCAP) cand[w][off] = vv[t];
              wsum += vv[t] - gmax;
            }
            cnt += __popcll(bal);        // ballot is uniform -> no atomic needed
          }
        }
      }
      wsum = wave_sum(wsum);
      const int c = cnt;                 // >= 1 (max element always passes)

      float tau;
      if (c <= 64) {
        // exact rank-sort + shfl prefix-scan + ballot solve (every wave)
        const float v = (lane < c) ? cand[w][lane] - gmax : 0.0f;
        int rank = 0;
        for (int q = 0; q < c; ++q) {
          const float t = cand[w][q] - gmax;
          rank += (t > v) || (t == v && q < lane);   // unique ranks
        }
        if (lane < c) sorted_[w][rank] = v;          // sorted_[w][0] == 0
        const float sv = (lane < c) ? sorted_[w][lane] : 0.0f;  // same-wave DS: in-order
        float cs = sv;
#pragma unroll
        for (int o = 1; o < 64; o <<= 1) {           // inclusive prefix scan
          const float t2 = __shfl_up(cs, o);
          if (lane >= o) cs += t2;
        }
        const int flag = (lane < c) && (sv * (float)(lane + 1) > cs - 1.0f);
        const unsigned long long bal2 = __ballot(flag);  // lane 0 always true
        const int k = 63 - __clzll(bal2);                // support size - 1
        const float csk = __shfl(cs, k);
        tau = (csk - 1.0f) / (float)(k + 1);
      } else if (c <= CCAP) {
        // wave Michelot over LDS candidates
        tau = (wsum - 1.0f) / (float)c;
        int cnt2 = c;
        for (int it = 0; it < 64; ++it) {
          float s2 = 0.0f; int c2 = 0;
          for (int q = lane; q < c; q += 64) {
            const float vs = cand[w][q] - gmax;
            if (vs > tau) { s2 += vs; c2++; }
          }
          s2 = wave_sum(s2); c2 = wave_sum_i(c2);
          if (c2 == cnt2 || c2 == 0) break;
          tau = (s2 - 1.0f) / (float)c2; cnt2 = c2;
        }
      } else {
        // pathological path: Michelot on registers, wave-local (-inf never passes)
        tau = (wsum - 1.0f) / (float)c;
        int cnt2 = c;
        for (int it = 0; it < 64; ++it) {
          float s2 = 0.0f; int c2 = 0;
#pragma unroll
          for (int j = 0; j < WPT; ++j) {
            const float vv[4] = {r[j].x, r[j].y, r[j].z, r[j].w};
#pragma unroll
            for (int t = 0; t < 4; ++t) {
              const float vs = vv[t] - gmax;
              if (vs > tau) { s2 += vs; c2++; }
            }
          }
          s2 = wave_sum(s2); c2 = wave_sum_i(c2);
          if (c2 == cnt2 || c2 == 0) break;
          tau = (s2 - 1.0f) / (float)c2; cnt2 = c2;
        }
      }

      const float sub = tau + gmax;      // unshifted threshold

      // ---- phase 3: store (vector interior, scalar boundary quads) ----
#pragma unroll
      for (int j = 0; j < WPT; ++j) {
        const int idx = a0 + (j * 64 + lane) * 4;
        if (idx >= e) continue;
        if (idx >= s && idx + 4 <= e) {
          float4 o4;
          o4.x = fmaxf(r[j].x - sub, 0.0f);
          o4.y = fmaxf(r[j].y - sub, 0.0f);
          o4.z = fmaxf(r[j].z - sub, 0.0f);
          o4.w = fmaxf(r[j].w - sub, 0.0f);
          *(float4*)(out + idx) = o4;
        } else {
          const float vv[4] = {r[j].x, r[j].y, r[j].z, r[j].w};
#pragma unroll
          for (int t = 0; t < 4; ++t) {
            const int p2 = idx + t;
            if (p2 >= s && p2 < e) out[p2] = fmaxf(vv[t] - sub, 0.0f);
          }
        }
      }
    } else {
      // ---- n > capacity fallback: wave-strided global Michelot (no barriers) ----
      float gmax = -INFINITY;
      for (int i = s + lane; i < e; i += 64) gmax = fmaxf(gmax, x[i]);
      gmax = wave_max(gmax);
      float bs = 0.0f; int bc = 0;
      for (int i = s + lane; i < e; i += 64) {
        const float vs = x[i] - gmax;
        if (vs > -1.0f) { bs += vs; bc++; }
      }
      bs = wave_sum(bs); bc = wave_sum_i(bc);
      float tau = (bs - 1.0f) / (float)bc;
      int cntS = bc;
      for (int it = 0; it < 64; ++it) {
        float s2 = 0.0f; int c2 = 0;
        for (int i = s + lane; i < e; i += 64) {
          const float vs = x[i] - gmax;
          if (vs > tau) { s2 += vs; c2++; }
        }
        s2 = wave_sum(s2); c2 = wave_sum_i(c2);
        if (c2 == cntS || c2 == 0) break;
        tau = (s2 - 1.0f) / (float)c2; cntS = c2;
      }
      const float sub = tau + gmax;
      for (int i = s + lane; i < e; i += 64) out[i] = fmaxf(x[i] - sub, 0.0f);
    }
  }
}

extern "C" void kernel_launch(void* const* d_in, const int* in_sizes, int n_in,
                              void* d_out, int out_size, void* d_ws, size_t ws_size,
                              hipStream_t stream) {
  const float* x     = (const float*)d_in[0];
  const int*   batch = (const int*)d_in[1];   // int32 on device (JAX x64 disabled)
  const int*   pB    = (const int*)d_in[2];
  float*       out   = (float*)d_out;
  const int N = in_sizes[0];

  int* starts = (int*)d_ws;                    // 4*(B+1) bytes of scratch

  const int K  = (N + SSTR - 1) / SSTR;        // sample intervals
  const int g1 = (K + 255) / 256;              // 256 intervals per block (4 waves x 64)
  build_starts_sampled<<<dim3(g1), dim3(256), 0, stream>>>(batch, starts, pB, N);
  // one wave per group: 1024 blocks x 4 waves = 4096 waves; grid-strides if B > 16384
  sparsemax_groups<<<dim3(1024), dim3(BLK), 0, stream>>>(x, starts, pB, out, N);
}

// Round 4
// 111.380 us; speedup vs baseline: 1.1244x; 1.0673x over previous
//
#include <hip/hip_runtime.h>

#define BLK 256
#define QPT 3                   // float4 per thread -> 3072-element capacity per block
#define CAPB (QPT * BLK * 4)    // 3072
#define CCAP 320                // candidate buffer: c<=64 exact; <=CCAP wave-Michelot; else block Michelot

// ---------- wave-local reductions (64-lane) ----------

__device__ __forceinline__ float wave_max(float v) {
#pragma unroll
  for (int o = 32; o; o >>= 1) v = fmaxf(v, __shfl_xor(v, o));
  return v;
}
__device__ __forceinline__ float wave_sum(float v) {
#pragma unroll
  for (int o = 32; o; o >>= 1) v += __shfl_xor(v, o);
  return v;
}
__device__ __forceinline__ int wave_sum_i(int v) {
#pragma unroll
  for (int o = 32; o; o >>= 1) v += __shfl_xor(v, o);
  return v;
}

__device__ __forceinline__ void block_sum_cnt(float& s, int& c, float* redf, int* redi, int tid) {
  s = wave_sum(s); c = wave_sum_i(c);
  __syncthreads();
  if ((tid & 63) == 0) { redf[tid >> 6] = s; redi[tid >> 6] = c; }
  __syncthreads();
  s = redf[0] + redf[1] + redf[2] + redf[3];
  c = redi[0] + redi[1] + redi[2] + redi[3];
}

// ---------- kernel 1: boundary detect -> starts[0..B], int4-vectorized ----------
// Coalesced stream of the whole batch array. Measured better than the
// 65-ary wave-search variant (prev session R5 112.4 vs R7/R8/R9 114-118),
// better than this session's R2 fused in-kernel binary search (125.2), and
// better than R3's stride-64 sampled refine (118.9): the fully-coalesced
// stream beats every scattered/latency-bound alternative tried.

extern "C" __global__ void __launch_bounds__(256)
build_starts(const int* __restrict__ batch, int* __restrict__ starts,
             const int* __restrict__ pB, int N) {
  const int B = *pB;
  const long long tid = (long long)blockIdx.x * 256 + threadIdx.x;
  const long long i0 = tid * 8;
  if (i0 >= N) return;
  int v[8];
  if (i0 + 8 <= N) {
    const int4 a = *(const int4*)(batch + i0);
    const int4 b = *(const int4*)(batch + i0 + 4);
    v[0] = a.x; v[1] = a.y; v[2] = a.z; v[3] = a.w;
    v[4] = b.x; v[5] = b.y; v[6] = b.z; v[7] = b.w;
  } else {
#pragma unroll
    for (int t = 0; t < 8; ++t) v[t] = (i0 + t < N) ? batch[i0 + t] : 0;
  }
  int prev = (i0 == 0) ? -1 : batch[i0 - 1];   // same cacheline as neighbor: L1 hit
#pragma unroll
  for (int t = 0; t < 8; ++t) {
    if (i0 + t >= N) break;
    const int cur = v[t];
    for (int g = prev + 1; g <= cur; ++g) starts[g] = (int)(i0 + t);
    prev = cur;
  }
  if (i0 + 8 >= N) {
    for (int g = prev + 1; g <= B; ++g) starts[g] = N;
  }
}

// ---------- kernel 2: one BLOCK (4 waves) per group, 3 barriers ----------
// tau >= -1 bound (outputs sum to 1) => support subset of {x > gmax-1};
// ballot-compact (~25 cands for Gaussian n=2048) into LDS, exact rank-sort
// + shfl prefix-scan + ballot solve on wave 0. Payload stays in registers.
// NOTE: R1's zero-barrier wave-per-group variant measured 113.4 vs this 112.0
// (tie within noise) -- total time is dominated by ~85 us of harness poison
// fills, so kernel-2 structure is not the lever. This is the measured-best.

extern "C" __global__ void __launch_bounds__(BLK)
sparsemax_groups(const float* __restrict__ x, const int* __restrict__ starts,
                 const int* __restrict__ pB, float* __restrict__ out, int N) {
  __shared__ float redf[4];
  __shared__ int   redi[4];
  __shared__ float cand[CCAP];
  __shared__ float sorted[64];
  __shared__ int   s_cnt;
  __shared__ float s_csum;
  __shared__ float s_tau;
  const int tid  = threadIdx.x;
  const int lane = tid & 63;
  const int w    = tid >> 6;
  const int B = *pB;

  for (int g = blockIdx.x; g < B; g += gridDim.x) {
    const int s = starts[g];
    const int e = starts[g + 1];
    const int n = e - s;
    if (n <= 0) continue;
    const int a0 = s & ~3;               // 16B-aligned load base

    if (e - a0 <= CAPB) {
      // ---- phase 1: aligned float4 global -> registers, fused max ----
      float4 r[QPT];
      float lmax = -INFINITY;
#pragma unroll
      for (int j = 0; j < QPT; ++j) {
        const int idx = a0 + (j * BLK + tid) * 4;
        float4 v = make_float4(-INFINITY, -INFINITY, -INFINITY, -INFINITY);
        if (idx < e) {
          if (idx + 4 <= N) {
            v = *(const float4*)(x + idx);
          } else {                        // buffer tail (last group only)
            if (idx + 0 < N) v.x = x[idx + 0];
            if (idx + 1 < N) v.y = x[idx + 1];
            if (idx + 2 < N) v.z = x[idx + 2];
            if (idx + 3 < N) v.w = x[idx + 3];
          }
          if (idx + 0 < s || idx + 0 >= e) v.x = -INFINITY;  // mask other groups
          if (idx + 1 < s || idx + 1 >= e) v.y = -INFINITY;
          if (idx + 2 < s || idx + 2 >= e) v.z = -INFINITY;
          if (idx + 3 < s || idx + 3 >= e) v.w = -INFINITY;
        }
        r[j] = v;
        lmax = fmaxf(lmax, fmaxf(fmaxf(v.x, v.y), fmaxf(v.z, v.w)));
      }
      lmax = wave_max(lmax);
      if (lane == 0) redf[w] = lmax;
      if (tid == 0) { s_cnt = 0; s_csum = 0.0f; }
      __syncthreads();                   // barrier 1
      const float gmax = fmaxf(fmaxf(redf[0], redf[1]), fmaxf(redf[2], redf[3]));
      const float thr = gmax - 1.0f;

      // ---- phase 2: ballot compaction, ONE LDS atomic per wave per component ----
      float wsum = 0.0f;                 // this lane's candidate sum (shifted)
#pragma unroll
      for (int j = 0; j < QPT; ++j) {
        const float vv[4] = {r[j].x, r[j].y, r[j].z, r[j].w};
#pragma unroll
        for (int t = 0; t < 4; ++t) {
          const bool p = vv[t] > thr;
          const unsigned long long bal = __ballot(p);
          if (bal) {
            int base = 0;
            if (lane == 0) base = atomicAdd(&s_cnt, __popcll(bal));
            base = __shfl(base, 0);
            if (p) {
              const int off = base + __popcll(bal & ((1ull << lane) - 1ull));
              if (off < CCAP) cand[off] = vv[t];
              wsum += vv[t] - gmax;
            }
          }
        }
      }
      wsum = wave_sum(wsum);
      if (lane == 0) atomicAdd(&s_csum, wsum);
      __syncthreads();                   // barrier 2
      const int c = s_cnt;               // >= 1 (max element always passes)

      if (c <= 64) {
        if (w == 0) {                    // exact solve on wave 0
          const float v = (lane < c) ? cand[lane] - gmax : 0.0f;
          int rank = 0;
          for (int q = 0; q < c; ++q) {
            const float t = cand[q] - gmax;
            rank += (t > v) || (t == v && q < lane);  // unique ranks
          }
          if (lane < c) sorted[rank] = v;             // sorted[0] == 0
          const float sv = (lane < c) ? sorted[lane] : 0.0f;
          float cs = sv;
#pragma unroll
          for (int o = 1; o < 64; o <<= 1) {          // inclusive prefix scan
            const float t2 = __shfl_up(cs, o);
            if (lane >= o) cs += t2;
          }
          const int flag = (lane < c) && (sv * (float)(lane + 1) > cs - 1.0f);
          const unsigned long long bal2 = __ballot(flag);  // lane 0 always true
          const int k = 63 - __clzll(bal2);                // support size - 1
          const float csk = __shfl(cs, k);
          if (lane == 0) s_tau = (csk - 1.0f) / (float)(k + 1);
        }
      } else if (c <= CCAP) {
        if (w == 0) {                    // wave-0 Michelot over LDS candidates
          float tau = (s_csum - 1.0f) / (float)c;
          int cnt = c;
          for (int it = 0; it < 64; ++it) {
            float s2 = 0.0f; int c2 = 0;
            for (int q = lane; q < c; q += 64) {
              const float vs = cand[q] - gmax;
              if (vs > tau) { s2 += vs; c2++; }
            }
            s2 = wave_sum(s2); c2 = wave_sum_i(c2);
            if (c2 == cnt || c2 == 0) break;
            tau = (s2 - 1.0f) / (float)c2; cnt = c2;
          }
          if (lane == 0) s_tau = tau;
        }
      } else {
        // block-uniform pathological path: Michelot on registers (has barriers)
        float tau = (s_csum - 1.0f) / (float)c;
        int cnt = c;
        for (int it = 0; it < 64; ++it) {
          float s2 = 0.0f; int c2 = 0;
#pragma unroll
          for (int j = 0; j < QPT; ++j) {
            const float vv[4] = {r[j].x, r[j].y, r[j].z, r[j].w};
#pragma unroll
            for (int t = 0; t < 4; ++t) {
              const float vs = vv[t] - gmax;            // -inf never passes
              if (vs > tau) { s2 += vs; c2++; }
            }
          }
          block_sum_cnt(s2, c2, redf, redi, tid);
          if (c2 == cnt || c2 == 0) break;
          tau = (s2 - 1.0f) / (float)c2; cnt = c2;
        }
        if (tid == 0) s_tau = tau;
      }
      __syncthreads();                   // barrier 3
      const float sub = s_tau + gmax;    // unshifted threshold

      // ---- phase 3: store (vector interior, scalar boundary quads) ----
#pragma unroll
      for (int j = 0; j < QPT; ++j) {
        const int idx = a0 + (j * BLK + tid) * 4;
        if (idx >= e) continue;
        if (idx >= s && idx + 4 <= e) {
          float4 o4;
          o4.x = fmaxf(r[j].x - sub, 0.0f);
          o4.y = fmaxf(r[j].y - sub, 0.0f);
          o4.z = fmaxf(r[j].z - sub, 0.0f);
          o4.w = fmaxf(r[j].w - sub, 0.0f);
          *(float4*)(out + idx) = o4;
        } else {
          const float vv[4] = {r[j].x, r[j].y, r[j].z, r[j].w};
#pragma unroll
          for (int t = 0; t < 4; ++t) {
            const int p2 = idx + t;
            if (p2 >= s && p2 < e) out[p2] = fmaxf(vv[t] - sub, 0.0f);
          }
        }
      }
    } else {
      // ---- n > capacity fallback: block-strided global Michelot ----
      float gmax = -INFINITY;
      for (int i = s + tid; i < e; i += BLK) gmax = fmaxf(gmax, x[i]);
      gmax = wave_max(gmax);
      if (lane == 0) redf[w] = gmax;
      __syncthreads();
      gmax = fmaxf(fmaxf(redf[0], redf[1]), fmaxf(redf[2], redf[3]));
      float bs = 0.0f; int bc = 0;
      for (int i = s + tid; i < e; i += BLK) {
        const float vs = x[i] - gmax;
        if (vs > -1.0f) { bs += vs; bc++; }
      }
      block_sum_cnt(bs, bc, redf, redi, tid);
      float tau = (bs - 1.0f) / (float)bc;
      int cntS = bc;
      for (int it = 0; it < 64; ++it) {
        float s2 = 0.0f; int c2 = 0;
        for (int i = s + tid; i < e; i += BLK) {
          const float vs = x[i] - gmax;
          if (vs > tau) { s2 += vs; c2++; }
        }
        block_sum_cnt(s2, c2, redf, redi, tid);
        if (c2 == cntS || c2 == 0) break;
        tau = (s2 - 1.0f) / (float)c2; cntS = c2;
      }
      const float sub = tau + gmax;
      for (int i = s + tid; i < e; i += BLK) out[i] = fmaxf(x[i] - sub, 0.0f);
    }
  }
}

extern "C" void kernel_launch(void* const* d_in, const int* in_sizes, int n_in,
                              void* d_out, int out_size, void* d_ws, size_t ws_size,
                              hipStream_t stream) {
  const float* x     = (const float*)d_in[0];
  const int*   batch = (const int*)d_in[1];   // int32 on device (JAX x64 disabled)
  const int*   pB    = (const int*)d_in[2];
  float*       out   = (float*)d_out;
  const int N = in_sizes[0];

  int* starts = (int*)d_ws;                    // 4*(B+1) bytes of scratch

  const int g1 = (N + 2047) / 2048;            // 8 elems/thread, 256 threads
  build_starts<<<dim3(g1), dim3(256), 0, stream>>>(batch, starts, pB, N);
  // one block (4 waves) per group; grid-strides if B > 4096
  sparsemax_groups<<<dim3(4096), dim3(BLK), 0, stream>>>(x, starts, pB, out, N);
}